// Round 4
// baseline (77.450 us; speedup 1.0000x reference)
//
#include <hip/hip_runtime.h>
#include <float.h>

#define NT 4096     // num tracks
#define NTOP 4
#define EMB 8

// lexicographic (d, j) strict less-than: smaller distance first, ties -> smaller j
#define LEXLT(da, ja, db, jb) (((da) < (db)) || (((da) == (db)) && ((ja) < (jb))))

__global__ __launch_bounds__(256) void nn_pool_kernel(
    const float* __restrict__ obs1,
    const float* __restrict__ obs2,
    const float* __restrict__ W,
    const float* __restrict__ bias,
    float* __restrict__ out)       // reference output dtype is FLOAT32
{
    __shared__ float2 s_pos[NT];   // 32 KB

    const int tid = threadIdx.x;
    const float2* g_pos = reinterpret_cast<const float2*>(obs2);
    #pragma unroll
    for (int k = 0; k < NT / 256; ++k)
        s_pos[tid + k * 256] = g_pos[tid + k * 256];
    __syncthreads();

    const int wave = tid >> 6;
    const int lane = tid & 63;
    const int row  = (blockIdx.x << 2) + wave;   // one wave per row

    const float2 pi = s_pos[row];

    // per-lane sorted top-4 by exact np-style distance: sqrt(dx*dx + dy*dy),
    // each op individually rounded f32 (no FMA contraction), so orderings and
    // rounding collisions match the numpy reference bit-for-bit.
    float bd0 = FLT_MAX, bd1 = FLT_MAX, bd2 = FLT_MAX, bd3 = FLT_MAX;
    int   bj0 = 0x7fffffff, bj1 = 0x7fffffff, bj2 = 0x7fffffff, bj3 = 0x7fffffff;

    #pragma unroll 4
    for (int k = 0; k < NT / 64; ++k) {
        const int j = lane + (k << 6);
        const float2 pj = s_pos[j];
        const float dx = __fsub_rn(pj.x, pi.x);
        const float dy = __fsub_rn(pj.y, pi.y);
        const float d2 = __fadd_rn(__fmul_rn(dx, dx), __fmul_rn(dy, dy));
        float d = __fsqrt_rn(d2);
        if (j == row) d = FLT_MAX;          // mask self

        const bool c3 = d < bd3;
        const bool c2 = d < bd2;
        const bool c1 = d < bd1;
        const bool c0 = d < bd0;
        bd3 = c3 ? (c2 ? bd2 : d) : bd3;   bj3 = c3 ? (c2 ? bj2 : j) : bj3;
        bd2 = c2 ? (c1 ? bd1 : d) : bd2;   bj2 = c2 ? (c1 ? bj1 : j) : bj2;
        bd1 = c1 ? (c0 ? bd0 : d) : bd1;   bj1 = c1 ? (c0 ? bj0 : j) : bj1;
        bd0 = c0 ? d : bd0;                bj0 = c0 ? j : bj0;
    }

    // butterfly merge across 64 lanes; each step merges two sorted 4-lists
    // (bitonic: mins of (a_k, b_{3-k}) then sort-4 of the bitonic low half)
    #pragma unroll
    for (int off = 1; off < 64; off <<= 1) {
        const float od0 = __shfl_xor(bd0, off, 64);
        const float od1 = __shfl_xor(bd1, off, 64);
        const float od2 = __shfl_xor(bd2, off, 64);
        const float od3 = __shfl_xor(bd3, off, 64);
        const int   oj0 = __shfl_xor(bj0, off, 64);
        const int   oj1 = __shfl_xor(bj1, off, 64);
        const int   oj2 = __shfl_xor(bj2, off, 64);
        const int   oj3 = __shfl_xor(bj3, off, 64);

        // low half of bitonic split: l_k = min(a_k, b_{3-k})
        float l0, l1, l2, l3; int m0, m1, m2, m3;
        { const bool t = LEXLT(od3, oj3, bd0, bj0); l0 = t ? od3 : bd0; m0 = t ? oj3 : bj0; }
        { const bool t = LEXLT(od2, oj2, bd1, bj1); l1 = t ? od2 : bd1; m1 = t ? oj2 : bj1; }
        { const bool t = LEXLT(od1, oj1, bd2, bj2); l2 = t ? od1 : bd2; m2 = t ? oj1 : bj2; }
        { const bool t = LEXLT(od0, oj0, bd3, bj3); l3 = t ? od0 : bd3; m3 = t ? oj0 : bj3; }

        // bitonic sort-4: CE(0,2) CE(1,3) CE(0,1) CE(2,3)
        { const bool t = LEXLT(l2, m2, l0, m0); float td=l0; int tj=m0;
          if (t) { l0=l2; m0=m2; l2=td; m2=tj; } }
        { const bool t = LEXLT(l3, m3, l1, m1); float td=l1; int tj=m1;
          if (t) { l1=l3; m1=m3; l3=td; m3=tj; } }
        { const bool t = LEXLT(l1, m1, l0, m0); float td=l0; int tj=m0;
          if (t) { l0=l1; m0=m1; l1=td; m1=tj; } }
        { const bool t = LEXLT(l3, m3, l2, m2); float td=l2; int tj=m2;
          if (t) { l2=l3; m2=m3; l3=td; m3=tj; } }

        bd0 = l0; bd1 = l1; bd2 = l2; bd3 = l3;
        bj0 = m0; bj1 = m1; bj2 = m2; bj3 = m3;
    }

    // all lanes now hold the global top-4 (ascending dist, ties by smaller j).
    // lanes 0..31: lane = t*8 + e  -> out[row, t*EMB + e]
    if (lane < 32) {
        const int t = lane >> 3;
        const int e = lane & 7;
        int j = (t == 0) ? bj0 : (t == 1) ? bj1 : (t == 2) ? bj2 : bj3;
        j &= (NT - 1);                        // OOB insurance (no-op when correct)

        const float2 pj = s_pos[j];
        const float2* g_o1 = reinterpret_cast<const float2*>(obs1);
        const float2 o1j = g_o1[j];
        const float2 o1i = g_o1[row];

        const float dx  = pj.x - pi.x;
        const float dy  = pj.y - pi.y;
        const float vjx = pj.x - o1j.x;
        const float vjy = pj.y - o1j.y;
        const float vix = pi.x - o1i.x;
        const float viy = pi.y - o1i.y;
        const float dvx = vjx - vix;
        const float dvy = vjy - viy;

        float acc = bias[e]
                  + dx  * W[0 * EMB + e]
                  + dy  * W[1 * EMB + e]
                  + dvx * W[2 * EMB + e]
                  + dvy * W[3 * EMB + e];
        out[row * 32 + lane] = fmaxf(acc, 0.0f);   // f32 store
    }
}

extern "C" void kernel_launch(void* const* d_in, const int* in_sizes, int n_in,
                              void* d_out, int out_size, void* d_ws, size_t ws_size,
                              hipStream_t stream) {
    // Resolve inputs BY SIZE (defensive; falls back to dict order).
    // Sizes: obs1=8192, obs2=8192 (first big = obs1), W=32, b=8.
    const float* obs1 = nullptr;
    const float* obs2 = nullptr;
    const float* W    = nullptr;
    const float* bias = nullptr;
    int big_seen = 0;
    for (int i = 0; i < n_in; ++i) {
        if (in_sizes[i] == 2 * NT) {
            if (big_seen++ == 0) obs1 = (const float*)d_in[i];
            else                 obs2 = (const float*)d_in[i];
        } else if (in_sizes[i] == 4 * EMB) {
            W = (const float*)d_in[i];
        } else if (in_sizes[i] == EMB) {
            bias = (const float*)d_in[i];
        }
    }
    if (!obs1 || !obs2 || !W || !bias) {
        obs1 = (const float*)d_in[0];
        obs2 = (const float*)d_in[1];
        W    = (const float*)d_in[2];
        bias = (const float*)d_in[3];
    }
    float* out = (float*)d_out;

    nn_pool_kernel<<<NT / 4, 256, 0, stream>>>(obs1, obs2, W, bias, out);
}